// Round 2
// baseline (331.720 us; speedup 1.0000x reference)
//
#include <hip/hip_runtime.h>

typedef unsigned short ushort_t;
typedef unsigned int uint_t;
typedef __attribute__((ext_vector_type(8))) short short8;
typedef __attribute__((ext_vector_type(4))) float float4v;

#define STRIDE 264      // LDS activation leading dim (bf16 elems); keeps 16B row align
#define NLAT   2048
#define DLAT   64

// d_ws layout (ushort units): [0..127] flag area (int at byte 0), then packed weights
#define PW_BASE 128
#define PW0_OFF 0        // 7 ktiles * 16 nt * 64 lanes * 8 = 57344
#define PW1_OFF 57344    // 8 ktiles -> 65536 each
#define PW2_OFF 122880
#define PW3_OFF 188416

__device__ __forceinline__ float b2f(ushort_t u) {
  union { uint_t i; float f; } v; v.i = ((uint_t)u) << 16; return v.f;
}
__device__ __forceinline__ ushort_t f2b(float f) {
  uint_t x = __float_as_uint(f);
  uint_t r = (x + 0x7fffu + ((x >> 16) & 1u)) >> 16;   // RNE
  return (ushort_t)r;
}
__device__ __forceinline__ int imin(int a, int b) { return a < b ? a : b; }
__device__ __forceinline__ int imax(int a, int b) { return a > b ? a : b; }

// dtype-generic scalar load -> fp32
__device__ __forceinline__ float ldv(const float* p, long i)    { return p[i]; }
__device__ __forceinline__ float ldv(const ushort_t* p, long i) { return b2f(p[i]); }
// dtype-generic scalar store from fp32
__device__ __forceinline__ void stv(float* p, long i, float v)    { p[i] = v; }
__device__ __forceinline__ void stv(ushort_t* p, long i, float v) { p[i] = f2b(v); }

// vector load of 16 consecutive elements -> fp32[16] (16B-aligned ptr required)
__device__ __forceinline__ void load16(const float* p, float* v) {
#pragma unroll
  for (int h = 0; h < 4; ++h) {
    float4 a = *(const float4*)(p + 4 * h);
    v[4 * h + 0] = a.x; v[4 * h + 1] = a.y; v[4 * h + 2] = a.z; v[4 * h + 3] = a.w;
  }
}
__device__ __forceinline__ void load16(const ushort_t* p, float* v) {
  uint4 a = *(const uint4*)p;
  uint4 b = *(const uint4*)(p + 8);
  uint_t w[8] = {a.x, a.y, a.z, a.w, b.x, b.y, b.z, b.w};
#pragma unroll
  for (int e = 0; e < 8; ++e) {
    v[2 * e]     = b2f((ushort_t)(w[e] & 0xffffu));
    v[2 * e + 1] = b2f((ushort_t)(w[e] >> 16));
  }
}

// ---------------------------------------------------------------------------
// Runtime dtype probe: bf16 latent ~ N(0,1) -> all |v| < ~5. fp32 latent read
// as bf16 pairs -> low halves have random exponents -> huge/NaN values.
// flag = 1 -> inputs are fp32; flag = 0 -> inputs are bf16.
// ---------------------------------------------------------------------------
__global__ void detect_mode(const ushort_t* __restrict__ lat, int* __restrict__ flag) {
  if (threadIdx.x == 0) *flag = 0;
  __syncthreads();
  int big = 0;
  for (int i = threadIdx.x; i < 1024; i += 64) {
    float v = b2f(lat[i]);
    if (!(fabsf(v) < 1e5f)) big = 1;   // catches huge and NaN
  }
  if (__any(big) && threadIdx.x == 0) *flag = 1;
}

// ---------------------------------------------------------------------------
// Pack weights into MFMA B-fragment order (bf16):
//   pw[((kt*16 + nt)*64 + lane)*8 + j] = W[k][n],
//   k = kt*32 + (lane>>4)*8 + j, n = nt*16 + (lane&15)
// W0 gets the feature-row permutation (sampled(192) | coord | pe(12) | 0-pad)
// and zero-fill to K=224.
// ---------------------------------------------------------------------------
template <typename TI>
__global__ void pack_w_t(const TI* __restrict__ W0, const TI* __restrict__ W1,
                         const TI* __restrict__ W2, const TI* __restrict__ W3,
                         ushort_t* __restrict__ pw, const int* __restrict__ flag, int want)
{
  if (*flag != want) return;
  int g = blockIdx.x * blockDim.x + threadIdx.x;
  if (g >= 31 * 1024) return;
  int lane = g & 63;
  int nt   = (g >> 6) & 15;
  int ktg  = g >> 10;                       // 0..30
  const TI* W; ushort_t* dst; int kt; bool isw0 = false;
  if (ktg < 7)       { W = W0; dst = pw + PW0_OFF; kt = ktg;      isw0 = true; }
  else if (ktg < 15) { W = W1; dst = pw + PW1_OFF; kt = ktg - 7;  }
  else if (ktg < 23) { W = W2; dst = pw + PW2_OFF; kt = ktg - 15; }
  else               { W = W3; dst = pw + PW3_OFF; kt = ktg - 23; }
  int n  = nt * 16 + (lane & 15);
  int kb = kt * 32 + (lane >> 4) * 8;
  uint_t words[4];
#pragma unroll
  for (int h = 0; h < 4; ++h) {
    int k0 = kb + 2 * h, k1 = k0 + 1;
    ushort_t lo, hi;
    if (isw0) {
      // permuted feature order: k'<192 -> orig 13+k' (sampled); k'==192 -> orig 0
      // (coord); 193..204 -> orig k'-192 (pe); >=205 -> zero pad
      int ko0 = (k0 < 192) ? (13 + k0) : (k0 == 192 ? 0 : (k0 < 205 ? k0 - 192 : -1));
      int ko1 = (k1 < 192) ? (13 + k1) : (k1 == 192 ? 0 : (k1 < 205 ? k1 - 192 : -1));
      lo = (ko0 >= 0) ? f2b(ldv(W, (long)ko0 * 256 + n)) : (ushort_t)0;
      hi = (ko1 >= 0) ? f2b(ldv(W, (long)ko1 * 256 + n)) : (ushort_t)0;
    } else {
      lo = f2b(ldv(W, (long)k0 * 256 + n));
      hi = f2b(ldv(W, (long)k1 * 256 + n));
    }
    words[h] = (uint_t)lo | ((uint_t)hi << 16);
  }
  uint4 o; o.x = words[0]; o.y = words[1]; o.z = words[2]; o.w = words[3];
  *(uint4*)(dst + ((size_t)(kt * 16 + nt) * 64 + lane) * 8) = o;
}

// ---------------------------------------------------------------------------
// One 256-wide MLP layer, in place in LDS.
// Wave (wr,wc) computes rows [wr*64,+64) x cols [wc*64,+64) with 4x4 16x16 tiles.
// ---------------------------------------------------------------------------
template <typename TI>
__device__ __forceinline__ void mlp_layer(ushort_t* hb, const ushort_t* __restrict__ pw,
                                          const TI* __restrict__ bias,
                                          int ktiles, int wr, int wc, int lane)
{
  float4v acc[4][4];
#pragma unroll
  for (int rt = 0; rt < 4; ++rt)
#pragma unroll
    for (int nt = 0; nt < 4; ++nt)
      acc[rt][nt] = (float4v){0.f, 0.f, 0.f, 0.f};

  const int rsel = lane & 15;
  const int q8   = (lane >> 4) * 8;
  for (int kt = 0; kt < ktiles; ++kt) {
    short8 a[4], bfrag[4];
#pragma unroll
    for (int rt = 0; rt < 4; ++rt)
      a[rt] = *(const short8*)&hb[(wr * 64 + rt * 16 + rsel) * STRIDE + kt * 32 + q8];
#pragma unroll
    for (int nt = 0; nt < 4; ++nt)
      bfrag[nt] = *(const short8*)(pw + ((size_t)(kt * 16 + wc * 4 + nt) * 64 + lane) * 8);
#pragma unroll
    for (int rt = 0; rt < 4; ++rt)
#pragma unroll
      for (int nt = 0; nt < 4; ++nt)
        acc[rt][nt] = __builtin_amdgcn_mfma_f32_16x16x32_bf16(a[rt], bfrag[nt], acc[rt][nt], 0, 0, 0);
  }
  __syncthreads();   // all reads of hb for this layer done before in-place writes
#pragma unroll
  for (int nt = 0; nt < 4; ++nt) {
    int col = wc * 64 + nt * 16 + rsel;
    float bv = ldv(bias, col);
#pragma unroll
    for (int rt = 0; rt < 4; ++rt) {
      int rbase = wr * 64 + rt * 16 + (lane >> 4) * 4;
#pragma unroll
      for (int r = 0; r < 4; ++r) {
        float v = acc[rt][nt][r] + bv;
        v = fmaxf(v, 0.0f);
        hb[(rbase + r) * STRIDE + col] = f2b(v);
      }
    }
  }
  __syncthreads();
}

// ---------------------------------------------------------------------------
// Fused kernel: feature build -> 4 MFMA layers (in-place LDS) -> final dot
// ---------------------------------------------------------------------------
template <typename TI>
__global__ __launch_bounds__(512, 4) void lisa_fused_t(
    const TI* __restrict__ coord, const TI* __restrict__ latent,
    const TI* __restrict__ bias0, const TI* __restrict__ bias1,
    const TI* __restrict__ bias2, const TI* __restrict__ bias3,
    const TI* __restrict__ W4,    const TI* __restrict__ b4,
    const ushort_t* __restrict__ pw, TI* __restrict__ out,
    const int* __restrict__ flag, int want)
{
  if (*flag != want) return;
  __shared__ ushort_t hb[128 * STRIDE];   // 67,584 B
  __shared__ float w4s[256];

  const int tid = threadIdx.x;
  const int row = tid >> 2;
  const int s   = tid & 3;
  const int p   = blockIdx.x * 128 + row;
  const int b   = p >> 15;                // / 32768

  if (tid < 256) w4s[tid] = ldv(W4, tid);

  // ---- feature build: hb[row][0..223] = [sampled(192) | coord | pe(12) | 0-pad]
  float c   = ldv(coord, p);
  float ix  = c * 2048.0f - 0.5f;
  float x0f = floorf(ix);
  float t   = ix - x0f;
  int   x0  = (int)x0f;
  int   i0  = imin(imax(x0, 0), NLAT - 1);
  int   i1  = imin(imax(x0 + 1, 0), NLAT - 1);
  int r0i[3], r1i[3];
  r0i[0] = imax(i0 - 1, 0);        r1i[0] = imax(i1 - 1, 0);        // prev channels
  r0i[1] = i0;                     r1i[1] = i1;                     // self
  r0i[2] = imin(i0 + 1, NLAT - 1); r1i[2] = imin(i1 + 1, NLAT - 1); // next
  const TI* lat = latent + (size_t)b * (NLAT * DLAT);
  float w0f = 1.0f - t, w1f = t;
#pragma unroll
  for (int reg = 0; reg < 3; ++reg) {
    float v0[16], v1[16];
    load16(lat + (long)r0i[reg] * DLAT + s * 16, v0);
    load16(lat + (long)r1i[reg] * DLAT + s * 16, v1);
    uint_t pk[8];
#pragma unroll
    for (int e = 0; e < 8; ++e) {
      float r0 = w0f * v0[2 * e]     + w1f * v1[2 * e];
      float r1 = w0f * v0[2 * e + 1] + w1f * v1[2 * e + 1];
      pk[e] = (uint_t)f2b(r0) | ((uint_t)f2b(r1) << 16);
    }
    uint4 o0; o0.x = pk[0]; o0.y = pk[1]; o0.z = pk[2]; o0.w = pk[3];
    uint4 o1; o1.x = pk[4]; o1.y = pk[5]; o1.z = pk[6]; o1.w = pk[7];
    *(uint4*)&hb[row * STRIDE + reg * 64 + s * 16]     = o0;
    *(uint4*)&hb[row * STRIDE + reg * 64 + s * 16 + 8] = o1;
  }
  if (s == 0) {
    hb[row * STRIDE + 192] = f2b(c);
    float f = 1.0f;
#pragma unroll
    for (int k = 0; k < 6; ++k) {
      float ang = c * f;
      hb[row * STRIDE + 193 + 2 * k] = f2b(sinf(ang));
      hb[row * STRIDE + 194 + 2 * k] = f2b(cosf(ang));
      f *= 2.0f;
    }
  } else if (s == 1) {
    for (int k = 205; k < 224; ++k) hb[row * STRIDE + k] = 0;
  }
  __syncthreads();

  // ---- 4 hidden layers ----
  const int lane = tid & 63;
  const int wv   = tid >> 6;
  const int wr   = wv >> 2;   // 0..1
  const int wc   = wv & 3;    // 0..3
  mlp_layer(hb, pw + PW0_OFF, bias0, 7, wr, wc, lane);
  mlp_layer(hb, pw + PW1_OFF, bias1, 8, wr, wc, lane);
  mlp_layer(hb, pw + PW2_OFF, bias2, 8, wr, wc, lane);
  mlp_layer(hb, pw + PW3_OFF, bias3, 8, wr, wc, lane);

  // ---- final 256 -> 1 dot (fp32 VALU) ----
  float partial = 0.f;
  const int kb = s * 64;
#pragma unroll
  for (int m = 0; m < 8; ++m) {
    uint4 hv = *(const uint4*)&hb[row * STRIDE + kb + m * 8];   // 8 bf16
    const float* wp = w4s + kb + m * 8;
    uint_t hw[4] = {hv.x, hv.y, hv.z, hv.w};
#pragma unroll
    for (int e = 0; e < 4; ++e) {
      partial += b2f((ushort_t)(hw[e] & 0xffffu)) * wp[2 * e];
      partial += b2f((ushort_t)(hw[e] >> 16))     * wp[2 * e + 1];
    }
  }
  partial += __shfl_xor(partial, 1, 64);
  partial += __shfl_xor(partial, 2, 64);
  if (s == 0) stv(out, p, partial + ldv(b4, 0));
}

extern "C" void kernel_launch(void* const* d_in, const int* in_sizes, int n_in,
                              void* d_out, int out_size, void* d_ws, size_t ws_size,
                              hipStream_t stream) {
  int* flag = (int*)d_ws;
  ushort_t* pw = (ushort_t*)d_ws + PW_BASE;

  detect_mode<<<1, 64, 0, stream>>>((const ushort_t*)d_in[1], flag);

  // fp32-input variant (flag==1)
  pack_w_t<float><<<62, 512, 0, stream>>>(
      (const float*)d_in[2], (const float*)d_in[4], (const float*)d_in[6],
      (const float*)d_in[8], pw, flag, 1);
  lisa_fused_t<float><<<2048, 512, 0, stream>>>(
      (const float*)d_in[0], (const float*)d_in[1],
      (const float*)d_in[3], (const float*)d_in[5], (const float*)d_in[7],
      (const float*)d_in[9], (const float*)d_in[10], (const float*)d_in[11],
      pw, (float*)d_out, flag, 1);

  // bf16-input variant (flag==0)
  pack_w_t<ushort_t><<<62, 512, 0, stream>>>(
      (const ushort_t*)d_in[2], (const ushort_t*)d_in[4], (const ushort_t*)d_in[6],
      (const ushort_t*)d_in[8], pw, flag, 0);
  lisa_fused_t<ushort_t><<<2048, 512, 0, stream>>>(
      (const ushort_t*)d_in[0], (const ushort_t*)d_in[1],
      (const ushort_t*)d_in[3], (const ushort_t*)d_in[5], (const ushort_t*)d_in[7],
      (const ushort_t*)d_in[9], (const ushort_t*)d_in[10], (const ushort_t*)d_in[11],
      pw, (ushort_t*)d_out, flag, 0);
}

// Round 3
// 324.325 us; speedup vs baseline: 1.0228x; 1.0228x over previous
//
#include <hip/hip_runtime.h>

typedef unsigned short ushort_t;
typedef unsigned int uint_t;
typedef __attribute__((ext_vector_type(8))) short short8;
typedef __attribute__((ext_vector_type(4))) float float4v;

#define STRIDE 264      // LDS activation leading dim (bf16 elems); keeps 16B row align
#define NLAT   2048
#define DLAT   64

// d_ws layout (ushort units): [0..127] flag area (int at byte 0), then packed weights
#define PW_BASE 128
#define PW0_OFF 0        // 7 ktiles * 16 nt * 64 lanes * 8 = 57344
#define PW1_OFF 57344    // 8 ktiles -> 65536 each
#define PW2_OFF 122880
#define PW3_OFF 188416

__device__ __forceinline__ float b2f(ushort_t u) {
  union { uint_t i; float f; } v; v.i = ((uint_t)u) << 16; return v.f;
}
__device__ __forceinline__ ushort_t f2b(float f) {
  uint_t x = __float_as_uint(f);
  uint_t r = (x + 0x7fffu + ((x >> 16) & 1u)) >> 16;   // RNE
  return (ushort_t)r;
}
__device__ __forceinline__ uint_t pack2(float lo, float hi) {
  return (uint_t)f2b(lo) | ((uint_t)f2b(hi) << 16);
}
__device__ __forceinline__ int imin(int a, int b) { return a < b ? a : b; }
__device__ __forceinline__ int imax(int a, int b) { return a > b ? a : b; }

// dtype-generic scalar load -> fp32
__device__ __forceinline__ float ldv(const float* p, long i)    { return p[i]; }
__device__ __forceinline__ float ldv(const ushort_t* p, long i) { return b2f(p[i]); }
// dtype-generic scalar store from fp32
__device__ __forceinline__ void stv(float* p, long i, float v)    { p[i] = v; }
__device__ __forceinline__ void stv(ushort_t* p, long i, float v) { p[i] = f2b(v); }

// ---------------------------------------------------------------------------
// lerp 16 consecutive elements from two rows, pack to bf16, store to LDS.
// Register-light: consumes each float4-sized chunk immediately (no address-
// taken locals -> no scratch).
// ---------------------------------------------------------------------------
__device__ __forceinline__ void lerp16_store(const float* p0, const float* p1,
                                             float w0, float w1, ushort_t* dst) {
  uint_t pk[8];
#pragma unroll
  for (int h = 0; h < 4; ++h) {
    float4 a = *(const float4*)(p0 + 4 * h);
    float4 b = *(const float4*)(p1 + 4 * h);
    pk[2 * h]     = pack2(w0 * a.x + w1 * b.x, w0 * a.y + w1 * b.y);
    pk[2 * h + 1] = pack2(w0 * a.z + w1 * b.z, w0 * a.w + w1 * b.w);
  }
  uint4 o0; o0.x = pk[0]; o0.y = pk[1]; o0.z = pk[2]; o0.w = pk[3];
  uint4 o1; o1.x = pk[4]; o1.y = pk[5]; o1.z = pk[6]; o1.w = pk[7];
  *(uint4*)dst       = o0;
  *(uint4*)(dst + 8) = o1;
}
__device__ __forceinline__ void lerp16_store(const ushort_t* p0, const ushort_t* p1,
                                             float w0, float w1, ushort_t* dst) {
  uint_t pk[8];
#pragma unroll
  for (int h = 0; h < 2; ++h) {
    uint4 a = *(const uint4*)(p0 + 8 * h);
    uint4 b = *(const uint4*)(p1 + 8 * h);
    uint_t aw[4] = {a.x, a.y, a.z, a.w};
    uint_t bw[4] = {b.x, b.y, b.z, b.w};
#pragma unroll
    for (int e = 0; e < 4; ++e) {
      float a0 = b2f((ushort_t)(aw[e] & 0xffffu)), a1 = b2f((ushort_t)(aw[e] >> 16));
      float c0 = b2f((ushort_t)(bw[e] & 0xffffu)), c1 = b2f((ushort_t)(bw[e] >> 16));
      pk[4 * h + e] = pack2(w0 * a0 + w1 * c0, w0 * a1 + w1 * c1);
    }
  }
  uint4 o0; o0.x = pk[0]; o0.y = pk[1]; o0.z = pk[2]; o0.w = pk[3];
  uint4 o1; o1.x = pk[4]; o1.y = pk[5]; o1.z = pk[6]; o1.w = pk[7];
  *(uint4*)dst       = o0;
  *(uint4*)(dst + 8) = o1;
}

// ---------------------------------------------------------------------------
// Runtime dtype probe: bf16 latent ~ N(0,1) -> all |v| < ~5. fp32 latent read
// as bf16 pairs -> low halves have random exponents -> huge/NaN values.
// flag = 1 -> inputs are fp32; flag = 0 -> inputs are bf16.
// ---------------------------------------------------------------------------
__global__ void detect_mode(const ushort_t* __restrict__ lat, int* __restrict__ flag) {
  if (threadIdx.x == 0) *flag = 0;
  __syncthreads();
  int big = 0;
  for (int i = threadIdx.x; i < 1024; i += 64) {
    float v = b2f(lat[i]);
    if (!(fabsf(v) < 1e5f)) big = 1;   // catches huge and NaN
  }
  if (__any(big) && threadIdx.x == 0) *flag = 1;
}

// ---------------------------------------------------------------------------
// Pack weights into MFMA B-fragment order (bf16):
//   pw[((kt*16 + nt)*64 + lane)*8 + j] = W[k][n],
//   k = kt*32 + (lane>>4)*8 + j, n = nt*16 + (lane&15)
// W0 gets the feature-row permutation (sampled(192) | coord | pe(12) | 0-pad)
// and zero-fill to K=224.
// ---------------------------------------------------------------------------
template <typename TI>
__global__ void pack_w_t(const TI* __restrict__ W0, const TI* __restrict__ W1,
                         const TI* __restrict__ W2, const TI* __restrict__ W3,
                         ushort_t* __restrict__ pw, const int* __restrict__ flag, int want)
{
  if (*flag != want) return;
  int g = blockIdx.x * blockDim.x + threadIdx.x;
  if (g >= 31 * 1024) return;
  int lane = g & 63;
  int nt   = (g >> 6) & 15;
  int ktg  = g >> 10;                       // 0..30
  const TI* W; ushort_t* dst; int kt; bool isw0 = false;
  if (ktg < 7)       { W = W0; dst = pw + PW0_OFF; kt = ktg;      isw0 = true; }
  else if (ktg < 15) { W = W1; dst = pw + PW1_OFF; kt = ktg - 7;  }
  else if (ktg < 23) { W = W2; dst = pw + PW2_OFF; kt = ktg - 15; }
  else               { W = W3; dst = pw + PW3_OFF; kt = ktg - 23; }
  int n  = nt * 16 + (lane & 15);
  int kb = kt * 32 + (lane >> 4) * 8;
  uint_t words[4];
#pragma unroll
  for (int h = 0; h < 4; ++h) {
    int k0 = kb + 2 * h, k1 = k0 + 1;
    ushort_t lo, hi;
    if (isw0) {
      // permuted feature order: k'<192 -> orig 13+k' (sampled); k'==192 -> orig 0
      // (coord); 193..204 -> orig k'-192 (pe); >=205 -> zero pad
      int ko0 = (k0 < 192) ? (13 + k0) : (k0 == 192 ? 0 : (k0 < 205 ? k0 - 192 : -1));
      int ko1 = (k1 < 192) ? (13 + k1) : (k1 == 192 ? 0 : (k1 < 205 ? k1 - 192 : -1));
      lo = (ko0 >= 0) ? f2b(ldv(W, (long)ko0 * 256 + n)) : (ushort_t)0;
      hi = (ko1 >= 0) ? f2b(ldv(W, (long)ko1 * 256 + n)) : (ushort_t)0;
    } else {
      lo = f2b(ldv(W, (long)k0 * 256 + n));
      hi = f2b(ldv(W, (long)k1 * 256 + n));
    }
    words[h] = (uint_t)lo | ((uint_t)hi << 16);
  }
  uint4 o; o.x = words[0]; o.y = words[1]; o.z = words[2]; o.w = words[3];
  *(uint4*)(dst + ((size_t)(kt * 16 + nt) * 64 + lane) * 8) = o;
}

// ---------------------------------------------------------------------------
// One 256-wide MLP layer, in place in LDS.
// Wave (wr,wc) computes rows [wr*64,+64) x cols [wc*64,+64) with 4x4 16x16 tiles.
// ---------------------------------------------------------------------------
template <typename TI>
__device__ __forceinline__ void mlp_layer(ushort_t* hb, const ushort_t* __restrict__ pw,
                                          const TI* __restrict__ bias,
                                          int ktiles, int wr, int wc, int lane)
{
  float4v acc[4][4];
#pragma unroll
  for (int rt = 0; rt < 4; ++rt)
#pragma unroll
    for (int nt = 0; nt < 4; ++nt)
      acc[rt][nt] = (float4v){0.f, 0.f, 0.f, 0.f};

  const int rsel = lane & 15;
  const int q8   = (lane >> 4) * 8;
  for (int kt = 0; kt < ktiles; ++kt) {
    short8 a[4], bfrag[4];
#pragma unroll
    for (int rt = 0; rt < 4; ++rt)
      a[rt] = *(const short8*)&hb[(wr * 64 + rt * 16 + rsel) * STRIDE + kt * 32 + q8];
#pragma unroll
    for (int nt = 0; nt < 4; ++nt)
      bfrag[nt] = *(const short8*)(pw + ((size_t)(kt * 16 + wc * 4 + nt) * 64 + lane) * 8);
#pragma unroll
    for (int rt = 0; rt < 4; ++rt)
#pragma unroll
      for (int nt = 0; nt < 4; ++nt)
        acc[rt][nt] = __builtin_amdgcn_mfma_f32_16x16x32_bf16(a[rt], bfrag[nt], acc[rt][nt], 0, 0, 0);
  }
  __syncthreads();   // all reads of hb for this layer done before in-place writes
#pragma unroll
  for (int nt = 0; nt < 4; ++nt) {
    int col = wc * 64 + nt * 16 + rsel;
    float bv = ldv(bias, col);
#pragma unroll
    for (int rt = 0; rt < 4; ++rt) {
      int rbase = wr * 64 + rt * 16 + (lane >> 4) * 4;
#pragma unroll
      for (int r = 0; r < 4; ++r) {
        float v = acc[rt][nt][r] + bv;
        v = fmaxf(v, 0.0f);
        hb[(rbase + r) * STRIDE + col] = f2b(v);
      }
    }
  }
  __syncthreads();
}

// ---------------------------------------------------------------------------
// Fused kernel: feature build -> 4 MFMA layers (in-place LDS) -> final dot
// ---------------------------------------------------------------------------
template <typename TI>
__global__ __launch_bounds__(512, 4) void lisa_fused_t(
    const TI* __restrict__ coord, const TI* __restrict__ latent,
    const TI* __restrict__ bias0, const TI* __restrict__ bias1,
    const TI* __restrict__ bias2, const TI* __restrict__ bias3,
    const TI* __restrict__ W4,    const TI* __restrict__ b4,
    const ushort_t* __restrict__ pw, TI* __restrict__ out,
    const int* __restrict__ flag, int want)
{
  if (*flag != want) return;
  __shared__ ushort_t hb[128 * STRIDE];   // 67,584 B
  __shared__ float w4s[256];

  const int tid = threadIdx.x;
  const int row = tid >> 2;
  const int s   = tid & 3;
  const int p   = blockIdx.x * 128 + row;
  const int b   = p >> 15;                // / 32768

  if (tid < 256) w4s[tid] = ldv(W4, tid);

  // ---- feature build: hb[row][0..223] = [sampled(192) | coord | pe(12) | 0-pad]
  float c   = ldv(coord, p);
  float ix  = c * 2048.0f - 0.5f;
  float x0f = floorf(ix);
  float t   = ix - x0f;
  int   x0  = (int)x0f;
  int   i0  = imin(imax(x0, 0), NLAT - 1);
  int   i1  = imin(imax(x0 + 1, 0), NLAT - 1);
  const TI* lat = latent + (size_t)b * (NLAT * DLAT);
  float w0f = 1.0f - t, w1f = t;
  {
    int r0 = imax(i0 - 1, 0), r1 = imax(i1 - 1, 0);          // prev channels
    lerp16_store(lat + (long)r0 * DLAT + s * 16, lat + (long)r1 * DLAT + s * 16,
                 w0f, w1f, &hb[row * STRIDE + 0 * 64 + s * 16]);
  }
  {
    lerp16_store(lat + (long)i0 * DLAT + s * 16, lat + (long)i1 * DLAT + s * 16,
                 w0f, w1f, &hb[row * STRIDE + 1 * 64 + s * 16]);
  }
  {
    int r0 = imin(i0 + 1, NLAT - 1), r1 = imin(i1 + 1, NLAT - 1);  // next channels
    lerp16_store(lat + (long)r0 * DLAT + s * 16, lat + (long)r1 * DLAT + s * 16,
                 w0f, w1f, &hb[row * STRIDE + 2 * 64 + s * 16]);
  }
  if (s == 0) {
    hb[row * STRIDE + 192] = f2b(c);
    float f = 1.0f;
#pragma unroll
    for (int k = 0; k < 6; ++k) {
      float ang = c * f;
      hb[row * STRIDE + 193 + 2 * k] = f2b(__sinf(ang));
      hb[row * STRIDE + 194 + 2 * k] = f2b(__cosf(ang));
      f *= 2.0f;
    }
  } else if (s == 1) {
    for (int k = 205; k < 224; ++k) hb[row * STRIDE + k] = 0;
  }
  __syncthreads();

  // ---- 4 hidden layers ----
  const int lane = tid & 63;
  const int wv   = tid >> 6;
  const int wr   = wv >> 2;   // 0..1
  const int wc   = wv & 3;    // 0..3
  mlp_layer(hb, pw + PW0_OFF, bias0, 7, wr, wc, lane);
  mlp_layer(hb, pw + PW1_OFF, bias1, 8, wr, wc, lane);
  mlp_layer(hb, pw + PW2_OFF, bias2, 8, wr, wc, lane);
  mlp_layer(hb, pw + PW3_OFF, bias3, 8, wr, wc, lane);

  // ---- final 256 -> 1 dot (fp32 VALU) ----
  float partial = 0.f;
  const int kb = s * 64;
#pragma unroll
  for (int m = 0; m < 8; ++m) {
    uint4 hv = *(const uint4*)&hb[row * STRIDE + kb + m * 8];   // 8 bf16
    const float* wp = w4s + kb + m * 8;
    uint_t hw[4] = {hv.x, hv.y, hv.z, hv.w};
#pragma unroll
    for (int e = 0; e < 4; ++e) {
      partial += b2f((ushort_t)(hw[e] & 0xffffu)) * wp[2 * e];
      partial += b2f((ushort_t)(hw[e] >> 16))     * wp[2 * e + 1];
    }
  }
  partial += __shfl_xor(partial, 1, 64);
  partial += __shfl_xor(partial, 2, 64);
  if (s == 0) stv(out, p, partial + ldv(b4, 0));
}

extern "C" void kernel_launch(void* const* d_in, const int* in_sizes, int n_in,
                              void* d_out, int out_size, void* d_ws, size_t ws_size,
                              hipStream_t stream) {
  int* flag = (int*)d_ws;
  ushort_t* pw = (ushort_t*)d_ws + PW_BASE;

  detect_mode<<<1, 64, 0, stream>>>((const ushort_t*)d_in[1], flag);

  // fp32-input variant (flag==1)
  pack_w_t<float><<<62, 512, 0, stream>>>(
      (const float*)d_in[2], (const float*)d_in[4], (const float*)d_in[6],
      (const float*)d_in[8], pw, flag, 1);
  lisa_fused_t<float><<<2048, 512, 0, stream>>>(
      (const float*)d_in[0], (const float*)d_in[1],
      (const float*)d_in[3], (const float*)d_in[5], (const float*)d_in[7],
      (const float*)d_in[9], (const float*)d_in[10], (const float*)d_in[11],
      pw, (float*)d_out, flag, 1);

  // bf16-input variant (flag==0)
  pack_w_t<ushort_t><<<62, 512, 0, stream>>>(
      (const ushort_t*)d_in[2], (const ushort_t*)d_in[4], (const ushort_t*)d_in[6],
      (const ushort_t*)d_in[8], pw, flag, 0);
  lisa_fused_t<ushort_t><<<2048, 512, 0, stream>>>(
      (const ushort_t*)d_in[0], (const ushort_t*)d_in[1],
      (const ushort_t*)d_in[3], (const ushort_t*)d_in[5], (const ushort_t*)d_in[7],
      (const ushort_t*)d_in[9], (const ushort_t*)d_in[10], (const ushort_t*)d_in[11],
      pw, (ushort_t*)d_out, flag, 0);
}